// Round 2
// baseline (1783.464 us; speedup 1.0000x reference)
//
#include <hip/hip_runtime.h>
#include <cstdint>
#include <cstddef>

// ---------------- problem constants ----------------
#define TGT   24
#define BS    16
#define SRC   400
#define VOCABN 32000
#define DIM   256
#define NROW  (TGT*BS)   // 384

typedef __bf16 bf16_t;
typedef __bf16 v8bf __attribute__((ext_vector_type(8)));
typedef float  v4f  __attribute__((ext_vector_type(4)));

// ---------------- prep: dtype conversions / transposes / gather ----------------
__global__ void k_prep(const float* __restrict__ Whh, const float* __restrict__ Wad,
                       const float* __restrict__ he,  const float* __restrict__ Wemb,
                       const float* __restrict__ Wproj, const float* __restrict__ Wae,
                       const float* __restrict__ Wih, const int* __restrict__ inputs,
                       bf16_t* o_whh, bf16_t* o_wad, bf16_t* o_he, bf16_t* o_wemb,
                       bf16_t* o_wprojT, bf16_t* o_wae, bf16_t* o_wih, bf16_t* o_embA)
{
    const long S0=262144, S1=65536, S2=1638400, S3=8192000, S4=196608, S5=65536, S6=262144, S7=98304;
    const long total = S0+S1+S2+S3+S4+S5+S6+S7;
    for (long i = (long)blockIdx.x*blockDim.x + threadIdx.x; i < total;
         i += (long)gridDim.x*blockDim.x) {
        long j = i;
        if (j < S0) { o_whh[j] = (bf16_t)Whh[j]; continue; }           j -= S0;
        if (j < S1) { o_wad[j] = (bf16_t)Wad[j]; continue; }           j -= S1;
        if (j < S2) { o_he[j] = (bf16_t)he[j]; continue; }             j -= S2;
        if (j < S3) { o_wemb[j] = (bf16_t)Wemb[j]; continue; }         j -= S3;
        if (j < S4) { long n = j>>8, k = j&255; o_wprojT[j] = (bf16_t)Wproj[k*768 + n]; continue; } j -= S4;
        if (j < S5) { o_wae[j] = (bf16_t)Wae[j]; continue; }           j -= S5;
        if (j < S6) { o_wih[j] = (bf16_t)Wih[j]; continue; }           j -= S6;
        { long r = j>>8, k = j&255; o_embA[j] = (bf16_t)Wemb[(long)inputs[r]*DIM + k]; }
    }
}

// ---------------- generic bf16 MFMA GEMM, 128x128 tile, BK=32 ----------------
// C[M,N] = A[M,K] @ B[N,K]^T   (both row-major, K-contiguous)
__global__ __launch_bounds__(256) void k_gemm(
    const bf16_t* __restrict__ A, const bf16_t* __restrict__ B,
    int M, int N, int K, int Ntiles, int mode,
    float* outF, bf16_t* outB,
    const float* __restrict__ bias0, const float* __restrict__ bias1,
    const int* __restrict__ padp)
{
    __shared__ bf16_t As[128*40];   // pitch 40 (pad 8) to break bank conflicts
    __shared__ bf16_t Bs[128*40];
    const int tid  = threadIdx.x;
    const int mt   = blockIdx.x / Ntiles, nt = blockIdx.x % Ntiles;
    const int m0   = mt*128, n0 = nt*128;
    const int lane = tid & 63, wave = tid >> 6;
    const int wm   = wave >> 1, wn = wave & 1;
    const int quad = lane >> 4, l16 = lane & 15;

    v4f acc[4][4];
#pragma unroll
    for (int i=0;i<4;i++)
#pragma unroll
        for (int j=0;j<4;j++) acc[i][j] = (v4f){0.f,0.f,0.f,0.f};

    const int srow = tid >> 1, shalf = tid & 1;       // staging: 2 threads/row
    const bf16_t* Ag = A + (long)(m0+srow)*K + shalf*16;
    const bf16_t* Bg = B + (long)(n0+srow)*K + shalf*16;
    bf16_t* AsW = &As[srow*40 + shalf*16];
    bf16_t* BsW = &Bs[srow*40 + shalf*16];

    for (int kc = 0; kc < K; kc += 32) {
        __syncthreads();
        uint4 a0 = *(const uint4*)(Ag + kc);
        uint4 a1 = *(const uint4*)(Ag + kc + 8);
        uint4 b0 = *(const uint4*)(Bg + kc);
        uint4 b1 = *(const uint4*)(Bg + kc + 8);
        *(uint4*)AsW = a0; *(uint4*)(AsW+8) = a1;
        *(uint4*)BsW = b0; *(uint4*)(BsW+8) = b1;
        __syncthreads();
        v8bf af[4], bb[4];
#pragma unroll
        for (int i=0;i<4;i++) {
            af[i] = *(const v8bf*)&As[(wm*64 + i*16 + l16)*40 + quad*8];
            bb[i] = *(const v8bf*)&Bs[(wn*64 + i*16 + l16)*40 + quad*8];
        }
#pragma unroll
        for (int i=0;i<4;i++)
#pragma unroll
            for (int j=0;j<4;j++)
                acc[i][j] = __builtin_amdgcn_mfma_f32_16x16x32_bf16(af[i], bb[j], acc[i][j], 0,0,0);
    }

    const int pad = padp ? *padp : -1;
#pragma unroll
    for (int i=0;i<4;i++) {
#pragma unroll
        for (int j=0;j<4;j++) {
#pragma unroll
            for (int r=0;r<4;r++) {
                const int gr = m0 + wm*64 + i*16 + quad*4 + r;   // C/D row = quad*4+reg
                const int gc = n0 + wn*64 + j*16 + l16;          // C/D col = lane&15
                const float v = acc[i][j][r];
                if (mode == 0)      outF[(long)gr*N + gc] = v + bias0[gc] + bias1[gc];
                else if (mode == 1) outB[(long)gr*N + gc] = (bf16_t)tanhf(v);
                else if (mode == 2) outB[(long)gr*N + gc] = (bf16_t)v;
                else {
                    float ex = (gc == pad) ? 0.f : __expf(v + bias0[gc]);
                    outF[(long)gr*N + gc] = ex;
                }
            }
        }
    }
}

// ---------------- per-b 16-block barrier (agent scope, cross-XCD safe) ----------------
__device__ __forceinline__ void grid16_barrier(int* cnt, int* gen) {
    __syncthreads();
    if (threadIdx.x == 0) {
        __threadfence();   // release: publish all prior global writes
        int g = __hip_atomic_load(gen, __ATOMIC_RELAXED, __HIP_MEMORY_SCOPE_AGENT);
        int v = __hip_atomic_fetch_add(cnt, 1, __ATOMIC_ACQ_REL, __HIP_MEMORY_SCOPE_AGENT);
        if (v == 15) {
            __hip_atomic_store(cnt, 0, __ATOMIC_RELAXED, __HIP_MEMORY_SCOPE_AGENT);
            __hip_atomic_fetch_add(gen, 1, __ATOMIC_ACQ_REL, __HIP_MEMORY_SCOPE_AGENT);
        } else {
            while (__hip_atomic_load(gen, __ATOMIC_ACQUIRE, __HIP_MEMORY_SCOPE_AGENT) == g)
                __builtin_amdgcn_s_sleep(1);
        }
        __threadfence();   // acquire: invalidate stale caches
    }
    __syncthreads();
}

// ---------------- recurrence v2: 16 blocks per batch elem, LDS-resident weights ----
// block = (b = blockIdx&15, p = blockIdx>>4). Part p owns d-slice [p*16,p*16+16)
// and s-slice [p*25,p*25+25). 3 inter-block barriers per step.
__global__ __launch_bounds__(256, 4) void k_rec2(
    const bf16_t* __restrict__ Whh, const bf16_t* __restrict__ Wad,
    const bf16_t* __restrict__ heg, const bf16_t* __restrict__ keg,
    const float* __restrict__ xg, const float* __restrict__ h0,
    const float* __restrict__ c0, const float* __restrict__ wu,
    float* __restrict__ hG, float* __restrict__ kdG, float* __restrict__ ceG,
    float* __restrict__ esumG, float* __restrict__ psG, float* __restrict__ edG,
    int* __restrict__ barv,
    bf16_t* __restrict__ feat, float* __restrict__ Ae)
{
    __shared__ bf16_t WhhS[64*264];   // 64 gate-rows x 256, pitch 264 (16B-aligned, 4-bank row shift)
    __shared__ bf16_t keS[25*264];
    __shared__ bf16_t heS[25*256];
    __shared__ float hS[DIM];
    __shared__ float histS[TGT][17];  // local d-slice of h history
    __shared__ float gateS[64];
    __shared__ float cS[16];
    __shared__ float EhistS[25];
    __shared__ float eeS[25];
    __shared__ float edS[TGT];
    __shared__ float cdS[16];
    __shared__ float miscS[2];        // [0]=1/esum, [1]=1/ed_denom

    const int b = blockIdx.x & 15;    // blockIdx%8 XCD round-robin keeps same-b parts on one XCD
    const int p = blockIdx.x >> 4;
    const int t = threadIdx.x;
    int* cnt = &barv[b*64];
    int* gen = cnt + 1;

    // ---- preload step-invariant slices into LDS ----
    for (int idx = t; idx < 2048; idx += 256) {       // Whh rows {g*256 + p*16 + dd}
        int lr = idx >> 5, ch = idx & 31;
        int gr = (lr >> 4)*256 + p*16 + (lr & 15);
        *(uint4*)&WhhS[lr*264 + ch*8] = *(const uint4*)&Whh[(size_t)gr*DIM + ch*8];
    }
    for (int idx = t; idx < 800; idx += 256) {        // ke/he rows s = p*25+si
        int si = idx >> 5, ch = idx & 31;
        int s = p*25 + si;
        *(uint4*)&keS[si*264 + ch*8] = *(const uint4*)&keg[((size_t)s*BS + b)*DIM + ch*8];
        *(uint4*)&heS[si*256 + ch*8] = *(const uint4*)&heg[((size_t)s*BS + b)*DIM + ch*8];
    }
    hS[t] = h0[b*DIM + t];
    if (t < 16) cS[t] = c0[b*DIM + p*16 + t];
    __syncthreads();

    for (int step = 0; step < TGT; ++step) {
        // ======== phase A: gates (64 rows x 256 dot) + LSTM cell for d-slice ========
        {
            const int lr = t >> 2, q = t & 3;         // 4 k-chunks of 8-interleave per row
            const int g = lr >> 4, dd = lr & 15;
            float xv = 0.f;
            if (q == 0) xv = xg[(size_t)(step*BS + b)*1024 + g*256 + p*16 + dd];
            float pa = 0.f;
#pragma unroll
            for (int m = 0; m < 8; ++m) {
                v8bf wv = *(const v8bf*)&WhhS[lr*264 + m*32 + q*8];
                float4 hv0 = *(const float4*)&hS[m*32 + q*8];
                float4 hv1 = *(const float4*)&hS[m*32 + q*8 + 4];
                pa += (float)wv[0]*hv0.x + (float)wv[1]*hv0.y + (float)wv[2]*hv0.z + (float)wv[3]*hv0.w
                    + (float)wv[4]*hv1.x + (float)wv[5]*hv1.y + (float)wv[6]*hv1.z + (float)wv[7]*hv1.w;
            }
            pa += __shfl_down(pa, 1);
            pa += __shfl_down(pa, 2);
            if (q == 0) gateS[lr] = pa + xv;
        }
        __syncthreads();
        if (t < 16) {
            float gi = gateS[t], gf = gateS[16+t], gg = gateS[32+t], go = gateS[48+t];
            float si_ = 1.f/(1.f+__expf(-gi));
            float sf  = 1.f/(1.f+__expf(-gf));
            float so  = 1.f/(1.f+__expf(-go));
            float cn  = sf*cS[t] + si_*tanhf(gg);
            float hn  = so*tanhf(cn);
            cS[t] = cn; histS[step][t] = hn;
            hG[b*DIM + p*16 + t] = hn;
        }
        grid16_barrier(cnt, gen);

        // ======== phase B: reload h; kd[d-slice]; enc scores; c_e partials ========
        const int ddk = t >> 4, qk = t & 15;
        uint4 wv0 = *(const uint4*)&Wad[((size_t)(p*16 + ddk))*DIM + qk*16];
        uint4 wv1 = *(const uint4*)&Wad[((size_t)(p*16 + ddk))*DIM + qk*16 + 8];
        hS[t] = hG[b*DIM + t];
        __syncthreads();
        {   // kd[d] = Wad[d,:] . h_step   (cached key for future intra-attn)
            v8bf a0 = __builtin_bit_cast(v8bf, wv0);
            v8bf a1 = __builtin_bit_cast(v8bf, wv1);
            float pa = 0.f;
#pragma unroll
            for (int i = 0; i < 8; ++i) pa += (float)a0[i]*hS[qk*16 + i];
#pragma unroll
            for (int i = 0; i < 8; ++i) pa += (float)a1[i]*hS[qk*16 + 8 + i];
            pa += __shfl_down(pa, 8); pa += __shfl_down(pa, 4);
            pa += __shfl_down(pa, 2); pa += __shfl_down(pa, 1);
            if (qk == 0) kdG[((size_t)b*TGT + step)*DIM + p*16 + ddk] = pa;
        }
        if (t < 200) {   // enc scores: 25 si x 8 qe
            const int si = t >> 3, qe = t & 7;
            float e = 0.f;
#pragma unroll
            for (int m = 0; m < 4; ++m) {
                v8bf kv = *(const v8bf*)&keS[si*264 + m*64 + qe*8];
                float4 hv0 = *(const float4*)&hS[m*64 + qe*8];
                float4 hv1 = *(const float4*)&hS[m*64 + qe*8 + 4];
                e += (float)kv[0]*hv0.x + (float)kv[1]*hv0.y + (float)kv[2]*hv0.z + (float)kv[3]*hv0.w
                   + (float)kv[4]*hv1.x + (float)kv[5]*hv1.y + (float)kv[6]*hv1.z + (float)kv[7]*hv1.w;
            }
            e += __shfl_down(e, 4); e += __shfl_down(e, 2); e += __shfl_down(e, 1);
            if (qe == 0) {
                float ex = __expf(e);
                float v;
                if (step == 0) { v = ex; EhistS[si] = ex; }
                else           { v = ex / EhistS[si]; EhistS[si] += ex; }
                eeS[si] = v;
            }
        }
        __syncthreads();
        if (t == 0) {
            float s = 0.f;
            for (int si2 = 0; si2 < 25; ++si2) s += eeS[si2];
            atomicAdd(&esumG[step*BS + b], s);
        }
        {   // c_e partial over this part's 25 s, all 256 d
            float pa = 0.f;
#pragma unroll 5
            for (int si2 = 0; si2 < 25; ++si2) pa += eeS[si2] * (float)heS[si2*256 + t];
            atomicAdd(&ceG[((size_t)step*BS + b)*DIM + t], pa);
        }
        grid16_barrier(cnt, gen);

        // ======== phase C: Ae out; intra-attn scores e_d[tau=p, p+16] ========
        if (t == 0) miscS[0] = 1.f / esumG[step*BS + b];
        __syncthreads();
        const float inv_es = miscS[0];
        if (t < 25) Ae[((size_t)step*BS + b)*SRC + p*25 + t] = eeS[t] * inv_es;
        {
            const int wv = t >> 6, ln = t & 63;
            const int tau = (wv == 0) ? p : p + 16;
            if (wv < 2 && tau <= step) {
                float4 kv = *(const float4*)&kdG[((size_t)b*TGT + tau)*DIM + ln*4];
                float e = kv.x*hS[ln*4] + kv.y*hS[ln*4+1] + kv.z*hS[ln*4+2] + kv.w*hS[ln*4+3];
#pragma unroll
                for (int o = 32; o > 0; o >>= 1) e += __shfl_down(e, o);
                if (ln == 0) edG[b*TGT + tau] = __expf(e);
            }
        }
        grid16_barrier(cnt, gen);

        // ======== phase D: intra softmax, c_d, feat, p_switch partial ========
        if (t < 64) {
            float v = (t <= step) ? edG[b*TGT + t] : 0.f;
            if (t < TGT) edS[t] = v;
#pragma unroll
            for (int o = 32; o > 0; o >>= 1) v += __shfl_down(v, o);
            if (t == 0) miscS[1] = 1.f / v;
        }
        __syncthreads();
        {
            const int dd = t >> 4, tq = t & 15;
            float cd = 0.f;
            for (int tau = tq; tau <= step; tau += 16) cd += edS[tau] * histS[tau][dd];
            cd += __shfl_down(cd, 8); cd += __shfl_down(cd, 4);
            cd += __shfl_down(cd, 2); cd += __shfl_down(cd, 1);
            if (tq == 0) cdS[dd] = cd * miscS[1];
        }
        __syncthreads();
        if (t < 16) {
            const int d = p*16 + t;
            const float hd = histS[step][t];
            const float ce = ceG[((size_t)step*BS + b)*DIM + d] * inv_es;
            const float cd = (step > 0) ? cdS[t] : 0.f;
            const size_t fr = ((size_t)step*BS + b)*768;
            feat[fr + d]         = (bf16_t)hd;
            feat[fr + DIM + d]   = (bf16_t)ce;
            feat[fr + 2*DIM + d] = (bf16_t)cd;
            float pw = hd*wu[d] + ce*wu[DIM + d] + cd*wu[2*DIM + d];
            pw += __shfl_down(pw, 8); pw += __shfl_down(pw, 4);
            pw += __shfl_down(pw, 2); pw += __shfl_down(pw, 1);
            if (t == 0) atomicAdd(&psG[step*BS + b], pw);   // raw sum; sigmoid deferred
        }
        __syncthreads();
    }
}

// ---------------- per-row softmax denom -> scale = sigmoid(psG+bu)/sum ----------------
__global__ __launch_bounds__(256) void k_rowsum(const float* __restrict__ ex,
                                                const float* __restrict__ psG,
                                                const float* __restrict__ bu,
                                                float* __restrict__ scale)
{
    __shared__ float red[4];
    const int r = blockIdx.x;
    const float4* p = (const float4*)(ex + (long)r*VOCABN);
    float s = 0.f;
    for (int i = threadIdx.x; i < VOCABN/4; i += 256) {
        float4 v = p[i];
        s += v.x + v.y + v.z + v.w;
    }
#pragma unroll
    for (int o=32;o>0;o>>=1) s += __shfl_down(s, o);
    if ((threadIdx.x & 63) == 0) red[threadIdx.x>>6] = s;
    __syncthreads();
    if (threadIdx.x == 0) {
        float ps = 1.f/(1.f+__expf(-(psG[r] + bu[0])));
        scale[r] = ps / (red[0]+red[1]+red[2]+red[3]);
    }
}

// ---------------- scores = exp_logits * scale[r] ----------------
__global__ void k_norm(float* __restrict__ out, const float* __restrict__ scale)
{
    const long n4 = (long)NROW*VOCABN/4;
    for (long i = (long)blockIdx.x*blockDim.x + threadIdx.x; i < n4;
         i += (long)gridDim.x*blockDim.x) {
        const long r = (i*4)/VOCABN;          // VOCABN % 4 == 0: no row straddle
        float4 v = ((float4*)out)[i];
        const float sc = scale[r];
        v.x*=sc; v.y*=sc; v.z*=sc; v.w*=sc;
        ((float4*)out)[i] = v;
    }
}

// ---------------- copy mechanism scatter ----------------
__global__ __launch_bounds__(256) void k_copy(float* __restrict__ out,
                                              const int* __restrict__ src,
                                              const float* __restrict__ Ae,
                                              const float* __restrict__ psG,
                                              const float* __restrict__ bu)
{
    const int r = blockIdx.x;        // r = t*BS + b
    const int b = r & (BS-1);
    const float p = 1.f/(1.f+__expf(-(psG[r] + bu[0])));
    for (int s = threadIdx.x; s < SRC; s += 256) {
        const int v = src[s*BS + b];
        atomicAdd(&out[(long)r*VOCABN + v], Ae[(long)r*SRC + s] * p);
    }
}

// ---------------- workspace layout (bytes, all 16B-aligned) ----------------
#define O_WHH    0u          // 524,288
#define O_WAD    524288u     // 131,072  (untransposed bf16 W_ad)
#define O_HE     655360u     // 3,276,800
#define O_KE     3932160u    // 3,276,800
#define O_WEMB   7208960u    // 16,384,000 (also overlaid by k_rec2 state after W_out GEMM)
#define O_WPROJT 23592960u   // 393,216
#define O_WIH    23986176u   // 524,288
#define O_EMBA   24510464u   // 196,608
#define O_WOUT   24707072u   // 49,152,000
#define O_XG     73859072u   // 1,572,864
#define O_FEAT   75431936u   // 589,824
#define O_AE     76021760u   // 614,400
#define O_SCALE  76637696u   // 1,536
#define O_WAE    76639232u   // 131,072
// --- overlay inside O_WEMB (W_emb bf16 dead after W_out GEMM) ---
#define O_HG     7208960u    // 16,384   BSxDIM f32
#define O_KD     7225344u    // 393,216  BSxTGTxDIM f32
#define O_CE     7618560u    // 393,216  TGTxBSxDIM f32  [zeroed]
#define O_ESUM   8011776u    // 1,536                   [zeroed]
#define O_PSG    8013312u    // 1,536                   [zeroed]
#define O_BAR    8014848u    // 4,096                   [zeroed]
#define O_ED     8018944u    // 1,536   BSxTGT f32
#define ZERO_OFF O_CE
#define ZERO_BYTES (393216u + 1536u + 1536u + 4096u)   // CE+ESUM+PSG+BAR contiguous

extern "C" void kernel_launch(void* const* d_in, const int* in_sizes, int n_in,
                              void* d_out, int out_size, void* d_ws, size_t ws_size,
                              hipStream_t stream)
{
    const int*   inputs = (const int*)  d_in[0];
    const int*   src    = (const int*)  d_in[1];
    const float* h_e    = (const float*)d_in[2];
    const float* h0     = (const float*)d_in[3];
    const float* c0     = (const float*)d_in[4];
    const float* W_emb  = (const float*)d_in[5];
    const float* W_ih   = (const float*)d_in[6];
    const float* b_ih   = (const float*)d_in[7];
    const float* W_hh   = (const float*)d_in[8];
    const float* b_hh   = (const float*)d_in[9];
    const float* W_ae   = (const float*)d_in[10];
    const float* W_ad   = (const float*)d_in[11];
    const float* W_proj = (const float*)d_in[12];
    const float* W_u    = (const float*)d_in[13];
    const float* b_u    = (const float*)d_in[14];
    const float* b_out  = (const float*)d_in[15];
    const int*   pad_id = (const int*)  d_in[16];

    char* w = (char*)d_ws;
    bf16_t* whh_bf  = (bf16_t*)(w + O_WHH);
    bf16_t* wad_bf  = (bf16_t*)(w + O_WAD);
    bf16_t* he_bf   = (bf16_t*)(w + O_HE);
    bf16_t* ke_bf   = (bf16_t*)(w + O_KE);
    bf16_t* wemb_bf = (bf16_t*)(w + O_WEMB);
    bf16_t* wprojT  = (bf16_t*)(w + O_WPROJT);
    bf16_t* wih_bf  = (bf16_t*)(w + O_WIH);
    bf16_t* embA_bf = (bf16_t*)(w + O_EMBA);
    bf16_t* wout_bf = (bf16_t*)(w + O_WOUT);
    float*  xg      = (float*) (w + O_XG);
    bf16_t* feat_bf = (bf16_t*)(w + O_FEAT);
    float*  Ae      = (float*) (w + O_AE);
    float*  scale   = (float*) (w + O_SCALE);
    bf16_t* wae_bf  = (bf16_t*)(w + O_WAE);
    float*  hG      = (float*) (w + O_HG);
    float*  kdG     = (float*) (w + O_KD);
    float*  ceG     = (float*) (w + O_CE);
    float*  esumG   = (float*) (w + O_ESUM);
    float*  psG     = (float*) (w + O_PSG);
    int*    barv    = (int*)   (w + O_BAR);
    float*  edG     = (float*) (w + O_ED);
    float*  out     = (float*)d_out;

    k_prep<<<1024, 256, 0, stream>>>(W_hh, W_ad, h_e, W_emb, W_proj, W_ae, W_ih, inputs,
                                     whh_bf, wad_bf, he_bf, wemb_bf, wprojT,
                                     wae_bf, wih_bf, embA_bf);
    // xg = embA @ W_ih^T + b_ih + b_hh        (M=384,  N=1024, K=256)
    k_gemm<<<3*8, 256, 0, stream>>>(embA_bf, wih_bf, NROW, 1024, 256, 8, 0,
                                    xg, nullptr, b_ih, b_hh, nullptr);
    // ke = h_e @ W_ae^T                        (M=6400, N=256,  K=256)
    k_gemm<<<50*2, 256, 0, stream>>>(he_bf, wae_bf, 6400, 256, 256, 2, 2,
                                     nullptr, ke_bf, nullptr, nullptr, nullptr);
    // W_out = tanh(W_emb @ W_proj)             (M=32000, N=768, K=256)
    k_gemm<<<250*6, 256, 0, stream>>>(wemb_bf, wprojT, VOCABN, 768, 256, 6, 1,
                                      nullptr, wout_bf, nullptr, nullptr, nullptr);
    // zero k_rec2 accumulators + barriers (overlay region; W_emb bf16 now dead)
    hipMemsetAsync(w + ZERO_OFF, 0, ZERO_BYTES, stream);
    // sequential decoder recurrence: 16 parts per batch elem
    k_rec2<<<256, 256, 0, stream>>>(whh_bf, wad_bf, he_bf, ke_bf, xg, h0, c0, W_u,
                                    hG, kdG, ceG, esumG, psG, edG, barv,
                                    feat_bf, Ae);
    // exp(logits + b_out), pad -> 0            (M=384, N=32000, K=768) -> d_out
    k_gemm<<<3*250, 256, 0, stream>>>(feat_bf, wout_bf, NROW, VOCABN, 768, 250, 3,
                                      out, nullptr, b_out, nullptr, pad_id);
    k_rowsum<<<NROW, 256, 0, stream>>>(out, psG, b_u, scale);
    k_norm<<<2048, 256, 0, stream>>>(out, scale);
    k_copy<<<NROW, 256, 0, stream>>>(out, src, Ae, psG, b_u);
}

// Round 3
// 628.840 us; speedup vs baseline: 2.8361x; 2.8361x over previous
//
#include <hip/hip_runtime.h>
#include <cstdint>
#include <cstddef>

// ---------------- problem constants ----------------
#define TGT   24
#define BS    16
#define SRC   400
#define VOCABN 32000
#define DIM   256
#define NROW  (TGT*BS)   // 384

typedef __bf16 bf16_t;
typedef __bf16 v8bf __attribute__((ext_vector_type(8)));
typedef float  v4f  __attribute__((ext_vector_type(4)));

// ---------------- prep: dtype conversions / transposes / gather ----------------
__global__ void k_prep(const float* __restrict__ Whh, const float* __restrict__ Wad,
                       const float* __restrict__ he,  const float* __restrict__ Wemb,
                       const float* __restrict__ Wproj, const float* __restrict__ Wae,
                       const float* __restrict__ Wih, const int* __restrict__ inputs,
                       bf16_t* o_whh, bf16_t* o_wadT, bf16_t* o_he, bf16_t* o_heT,
                       bf16_t* o_wae, bf16_t* o_wih, bf16_t* o_wprojT, bf16_t* o_embA)
{
    const long S0=262144, S1=65536, S2=1638400, S3=1638400, S4=65536, S5=262144, S6=196608, S7=98304;
    const long total = S0+S1+S2+S3+S4+S5+S6+S7;
    for (long i = (long)blockIdx.x*blockDim.x + threadIdx.x; i < total;
         i += (long)gridDim.x*blockDim.x) {
        long j = i;
        if (j < S0) { o_whh[j] = (bf16_t)Whh[j]; continue; }           j -= S0;
        if (j < S1) { long n = j>>8, k = j&255; o_wadT[j] = (bf16_t)Wad[k*DIM + n]; continue; } j -= S1;
        if (j < S2) { o_he[j] = (bf16_t)he[j]; continue; }             j -= S2;
        if (j < S3) { // heT[b][d][s] = he[(s*BS+b)*DIM+d]
            long b = j / 102400, rem = j % 102400, d = rem / 400, s = rem % 400;
            o_heT[j] = (bf16_t)he[(s*BS + b)*DIM + d]; continue; }     j -= S3;
        if (j < S4) { o_wae[j] = (bf16_t)Wae[j]; continue; }           j -= S4;
        if (j < S5) { o_wih[j] = (bf16_t)Wih[j]; continue; }           j -= S5;
        if (j < S6) { long n = j>>8, k = j&255; o_wprojT[j] = (bf16_t)Wproj[k*768 + n]; continue; } j -= S6;
        { long r = j>>8, k = j&255; o_embA[j] = (bf16_t)Wemb[(long)inputs[r]*DIM + k]; }
    }
}

// ---------------- generic bf16 MFMA GEMM, 128x128 tile, BK=32 ----------------
// C[M,N] = A[M,K] @ B[N,K]^T  (row-major, K-contiguous). A32!=null: A read fp32.
__global__ __launch_bounds__(256) void k_gemm(
    const bf16_t* __restrict__ A, const float* __restrict__ A32,
    const bf16_t* __restrict__ B,
    int M, int N, int K, int Ntiles, int mode,
    float* outF, bf16_t* outB,
    const float* __restrict__ bias0, const float* __restrict__ bias1,
    const int* __restrict__ padp)
{
    __shared__ bf16_t As[128*40];   // pitch 40 (pad 8) to break bank conflicts
    __shared__ bf16_t Bs[128*40];
    const int tid  = threadIdx.x;
    const int mt   = blockIdx.x / Ntiles, nt = blockIdx.x % Ntiles;
    const int m0   = mt*128, n0 = nt*128;
    const int lane = tid & 63, wave = tid >> 6;
    const int wm   = wave >> 1, wn = wave & 1;
    const int quad = lane >> 4, l16 = lane & 15;

    v4f acc[4][4];
#pragma unroll
    for (int i=0;i<4;i++)
#pragma unroll
        for (int j=0;j<4;j++) acc[i][j] = (v4f){0.f,0.f,0.f,0.f};

    const int srow = tid >> 1, shalf = tid & 1;       // staging: 2 threads/row
    const bf16_t* Ag   = A   ? A   + (size_t)(m0+srow)*K + shalf*16 : nullptr;
    const float*  Ag32 = A32 ? A32 + (size_t)(m0+srow)*K + shalf*16 : nullptr;
    const bf16_t* Bg = B + (size_t)(n0+srow)*K + shalf*16;
    bf16_t* AsW = &As[srow*40 + shalf*16];
    bf16_t* BsW = &Bs[srow*40 + shalf*16];

    for (int kc = 0; kc < K; kc += 32) {
        __syncthreads();
        uint4 b0 = *(const uint4*)(Bg + kc);
        uint4 b1 = *(const uint4*)(Bg + kc + 8);
        if (A32) {
            float4 f0 = *(const float4*)(Ag32 + kc);
            float4 f1 = *(const float4*)(Ag32 + kc + 4);
            float4 f2 = *(const float4*)(Ag32 + kc + 8);
            float4 f3 = *(const float4*)(Ag32 + kc + 12);
            v8bf u0, u1;
            u0[0]=(bf16_t)f0.x; u0[1]=(bf16_t)f0.y; u0[2]=(bf16_t)f0.z; u0[3]=(bf16_t)f0.w;
            u0[4]=(bf16_t)f1.x; u0[5]=(bf16_t)f1.y; u0[6]=(bf16_t)f1.z; u0[7]=(bf16_t)f1.w;
            u1[0]=(bf16_t)f2.x; u1[1]=(bf16_t)f2.y; u1[2]=(bf16_t)f2.z; u1[3]=(bf16_t)f2.w;
            u1[4]=(bf16_t)f3.x; u1[5]=(bf16_t)f3.y; u1[6]=(bf16_t)f3.z; u1[7]=(bf16_t)f3.w;
            *(v8bf*)AsW = u0; *(v8bf*)(AsW+8) = u1;
        } else {
            uint4 a0 = *(const uint4*)(Ag + kc);
            uint4 a1 = *(const uint4*)(Ag + kc + 8);
            *(uint4*)AsW = a0; *(uint4*)(AsW+8) = a1;
        }
        *(uint4*)BsW = b0; *(uint4*)(BsW+8) = b1;
        __syncthreads();
        v8bf af[4], bb[4];
#pragma unroll
        for (int i=0;i<4;i++) {
            af[i] = *(const v8bf*)&As[(wm*64 + i*16 + l16)*40 + quad*8];
            bb[i] = *(const v8bf*)&Bs[(wn*64 + i*16 + l16)*40 + quad*8];
        }
#pragma unroll
        for (int i=0;i<4;i++)
#pragma unroll
            for (int j=0;j<4;j++)
                acc[i][j] = __builtin_amdgcn_mfma_f32_16x16x32_bf16(af[i], bb[j], acc[i][j], 0,0,0);
    }

    const int pad = padp ? *padp : -1;
#pragma unroll
    for (int i=0;i<4;i++) {
#pragma unroll
        for (int j=0;j<4;j++) {
#pragma unroll
            for (int r=0;r<4;r++) {
                const int gr = m0 + wm*64 + i*16 + quad*4 + r;   // C/D row = quad*4+reg
                const int gc = n0 + wn*64 + j*16 + l16;          // C/D col = lane&15
                const float v = acc[i][j][r];
                if (mode == 0)      outF[(size_t)gr*N + gc] = v + bias0[gc] + bias1[gc];
                else if (mode == 1) outB[(size_t)gr*N + gc] = (bf16_t)tanhf(v);
                else if (mode == 2) outB[(size_t)gr*N + gc] = (bf16_t)v;
                else {
                    float ex = (gc == pad) ? 0.f : __expf(v + bias0[gc]);
                    outF[(size_t)gr*N + gc] = ex;
                }
            }
        }
    }
}

// ---------------- sequential LSTM chain: ONE block, MFMA gates ----------------
// gates[b][row] = xg + sum_d h[b][d] * Whh[row][d].  A = h (hi+lo bf16 split),
// B = Whh rows streamed from L2 (512 KB/step). Wave w owns tiles {w,w+16,w+32,w+48}
// i.e. gate rows {g*256 + w*16 + l16} -> each lane's 4 accs hold i,f,g,o for
// (b=quad*4+r, d=w*16+l16): cell update entirely in-register.
__global__ __launch_bounds__(1024) void k_lstm(
    const bf16_t* __restrict__ Whh, const float* __restrict__ xg,
    const float* __restrict__ h0, const float* __restrict__ c0,
    float* __restrict__ hallF, bf16_t* __restrict__ hallB)
{
    __shared__ bf16_t hhi[16][264];   // pitch 264: lane-stride 132 words -> 2-way max
    __shared__ bf16_t hlo[16][264];
    const int tid  = threadIdx.x;
    const int w    = tid >> 6, lane = tid & 63;
    const int l16  = lane & 15, quad = lane >> 4;
    const int dme  = w*16 + l16;

    for (int i = tid; i < 4096; i += 1024) {
        int b = i >> 8, d = i & 255;
        float v = h0[b*DIM + d];
        bf16_t hi = (bf16_t)v;
        hhi[b][d] = hi;
        hlo[b][d] = (bf16_t)(v - (float)hi);
    }
    float c[4];
#pragma unroll
    for (int r=0;r<4;r++) c[r] = c0[(quad*4+r)*DIM + dme];
    __syncthreads();

    for (int step = 0; step < TGT; ++step) {
        v4f acc[4];
#pragma unroll
        for (int g=0;g<4;g++) acc[g] = (v4f){0.f,0.f,0.f,0.f};
#pragma unroll
        for (int k=0;k<8;k++) {
            v8bf ahi = *(const v8bf*)&hhi[l16][k*32 + quad*8];
            v8bf alo = *(const v8bf*)&hlo[l16][k*32 + quad*8];
#pragma unroll
            for (int g=0;g<4;g++) {
                v8bf bw = *(const v8bf*)&Whh[(size_t)(g*256 + w*16 + l16)*DIM + k*32 + quad*8];
                acc[g] = __builtin_amdgcn_mfma_f32_16x16x32_bf16(ahi, bw, acc[g], 0,0,0);
                acc[g] = __builtin_amdgcn_mfma_f32_16x16x32_bf16(alo, bw, acc[g], 0,0,0);
            }
        }
        __syncthreads();     // all lanes done reading old h before rewrite
        const float* xgp = xg + (size_t)step*BS*1024;
#pragma unroll
        for (int r=0;r<4;r++) {
            const int b = quad*4 + r;
            const float gi = acc[0][r] + xgp[b*1024 +       dme];
            const float gf = acc[1][r] + xgp[b*1024 + 256 + dme];
            const float gg = acc[2][r] + xgp[b*1024 + 512 + dme];
            const float go = acc[3][r] + xgp[b*1024 + 768 + dme];
            const float si = 1.f/(1.f+__expf(-gi));
            const float sf = 1.f/(1.f+__expf(-gf));
            const float so = 1.f/(1.f+__expf(-go));
            const float cn = sf*c[r] + si*tanhf(gg);
            const float hn = so*tanhf(cn);
            c[r] = cn;
            const bf16_t hi = (bf16_t)hn;
            hhi[b][dme] = hi;
            hlo[b][dme] = (bf16_t)(hn - (float)hi);
            hallF[(size_t)(step*BS + b)*DIM + dme] = hn;
            hallB[(size_t)(step*BS + b)*DIM + dme] = hi;
        }
        __syncthreads();
    }
}

// ---------------- expE[t,b,s] = exp(ke[s,b,:] . h[t,b,:]) — fully parallel ------
__global__ __launch_bounds__(256) void k_escore(const bf16_t* __restrict__ ke,
                                                const float* __restrict__ hallF,
                                                float* __restrict__ expE)
{
    const int t = blockIdx.x >> 4, b = blockIdx.x & 15;
    const int tid = threadIdx.x;
    __shared__ float hS[DIM];
    hS[tid] = hallF[(size_t)(t*BS + b)*DIM + tid];
    __syncthreads();
    for (int s = tid; s < SRC; s += 256) {
        const v8bf* kp = (const v8bf*)(ke + ((size_t)s*BS + b)*DIM);
        float e = 0.f;
#pragma unroll 8
        for (int m=0;m<32;m++) {
            v8bf kv = kp[m];
#pragma unroll
            for (int i=0;i<8;i++) e += (float)kv[i]*hS[m*8+i];
        }
        expE[((size_t)t*BS + b)*SRC + s] = __expf(e);
    }
}

// ---------------- per-(t,b) attention tail: E_hist prefix, A_e, c_e, intra, feat --
__global__ __launch_bounds__(256) void k_attn2(
    const float* __restrict__ expE, const bf16_t* __restrict__ heT,
    const float* __restrict__ hallF, const bf16_t* __restrict__ qdG,
    const float* __restrict__ wu, const float* __restrict__ bu,
    bf16_t* __restrict__ feat, float* __restrict__ Ae, float* __restrict__ ps)
{
    const int t = blockIdx.x >> 4, b = blockIdx.x & 15;
    const int tid = threadIdx.x;
    __shared__ float hS[DIM], qdS[DIM], eeS[SRC], adS[TGT];
    __shared__ float red[4], misc[2];

    hS[tid]  = hallF[(size_t)(t*BS + b)*DIM + tid];
    qdS[tid] = (float)qdG[(size_t)(t*BS + b)*DIM + tid];
    __syncthreads();

    // EE with cumulative-exp trick (prefix over t' < t)
    for (int s = tid; s < SRC; s += 256) {
        float prev = 0.f;
        for (int tp = 0; tp < t; ++tp) prev += expE[((size_t)tp*BS + b)*SRC + s];
        float my = expE[((size_t)t*BS + b)*SRC + s];
        eeS[s] = (t == 0) ? my : my / prev;
    }
    __syncthreads();
    {   // esum
        float pa = 0.f;
        for (int s = tid; s < SRC; s += 256) pa += eeS[s];
#pragma unroll
        for (int o=32;o>0;o>>=1) pa += __shfl_down(pa, o);
        if ((tid & 63) == 0) red[tid>>6] = pa;
        __syncthreads();
        if (tid == 0) misc[0] = 1.f/(red[0]+red[1]+red[2]+red[3]);
        __syncthreads();
    }
    const float inv_es = misc[0];
    for (int s = tid; s < SRC; s += 256)
        Ae[((size_t)t*BS + b)*SRC + s] = eeS[s] * inv_es;

    // c_e[d] via transposed heT[b][d][s] (s-contiguous)
    float ce;
    {
        const v8bf* hp = (const v8bf*)(heT + ((size_t)b*DIM + tid)*SRC);
        float acc = 0.f;
#pragma unroll 10
        for (int m=0;m<50;m++) {
            v8bf hv = hp[m];
#pragma unroll
            for (int i=0;i<8;i++) acc += (float)hv[i]*eeS[m*8+i];
        }
        ce = acc * inv_es;
    }

    // intra-decoder scores: wave wv handles tau = wv, wv+4, ...
    {
        const int wv = tid >> 6, ln = tid & 63;
        for (int tau = wv; tau <= t; tau += 4) {
            float4 a = *(const float4*)(hallF + ((size_t)(tau*BS + b))*DIM + ln*4);
            float e = a.x*qdS[ln*4] + a.y*qdS[ln*4+1] + a.z*qdS[ln*4+2] + a.w*qdS[ln*4+3];
#pragma unroll
            for (int o=32;o>0;o>>=1) e += __shfl_down(e, o);
            if (ln == 0) adS[tau] = __expf(e);
        }
    }
    __syncthreads();
    if (tid < 64) {
        float v = (tid <= t) ? adS[tid] : 0.f;
#pragma unroll
        for (int o=32;o>0;o>>=1) v += __shfl_down(v, o);
        if (tid == 0) misc[1] = 1.f/v;
    }
    __syncthreads();
    float cd = 0.f;
    for (int tau = 0; tau <= t; ++tau)
        cd += adS[tau] * hallF[((size_t)(tau*BS + b))*DIM + tid];
    cd *= misc[1];
    if (t == 0) cd = 0.f;

    // feat + p_switch
    const float hd = hS[tid];
    const size_t fr = ((size_t)t*BS + b)*768;
    feat[fr + tid]       = (bf16_t)hd;
    feat[fr + 256 + tid] = (bf16_t)ce;
    feat[fr + 512 + tid] = (bf16_t)cd;
    float pw = hd*wu[tid] + ce*wu[256 + tid] + cd*wu[512 + tid];
#pragma unroll
    for (int o=32;o>0;o>>=1) pw += __shfl_down(pw, o);
    if ((tid & 63) == 0) red[tid>>6] = pw;
    __syncthreads();
    if (tid == 0) {
        float s = red[0]+red[1]+red[2]+red[3];
        ps[t*BS + b] = 1.f/(1.f+__expf(-(s + bu[0])));
    }
}

// ---------------- per-row softmax denom -> scale = ps/sum ----------------
__global__ __launch_bounds__(256) void k_rowsum(const float* __restrict__ ex,
                                                const float* __restrict__ ps,
                                                float* __restrict__ scale)
{
    __shared__ float red[4];
    const int r = blockIdx.x;
    const float4* p = (const float4*)(ex + (size_t)r*VOCABN);
    float s = 0.f;
    for (int i = threadIdx.x; i < VOCABN/4; i += 256) {
        float4 v = p[i];
        s += v.x + v.y + v.z + v.w;
    }
#pragma unroll
    for (int o=32;o>0;o>>=1) s += __shfl_down(s, o);
    if ((threadIdx.x & 63) == 0) red[threadIdx.x>>6] = s;
    __syncthreads();
    if (threadIdx.x == 0) scale[r] = ps[r] / (red[0]+red[1]+red[2]+red[3]);
}

// ---------------- scores = exp_logits * scale[r] ----------------
__global__ void k_norm(float* __restrict__ out, const float* __restrict__ scale)
{
    const long n4 = (long)NROW*VOCABN/4;
    for (long i = (long)blockIdx.x*blockDim.x + threadIdx.x; i < n4;
         i += (long)gridDim.x*blockDim.x) {
        const long r = (i*4)/VOCABN;
        float4 v = ((float4*)out)[i];
        const float sc = scale[r];
        v.x*=sc; v.y*=sc; v.z*=sc; v.w*=sc;
        ((float4*)out)[i] = v;
    }
}

// ---------------- copy mechanism scatter ----------------
__global__ __launch_bounds__(256) void k_copy(float* __restrict__ out,
                                              const int* __restrict__ src,
                                              const float* __restrict__ Ae,
                                              const float* __restrict__ ps)
{
    const int r = blockIdx.x;        // r = t*BS + b
    const int b = r & (BS-1);
    const float p = ps[r];
    for (int s = threadIdx.x; s < SRC; s += 256) {
        const int v = src[s*BS + b];
        atomicAdd(&out[(size_t)r*VOCABN + v], Ae[(size_t)r*SRC + s] * p);
    }
}

// ---------------- workspace layout (bytes, 16B-aligned), total 65.1 MB ----------
#define O_WHH    0u
#define O_WADT   524288u
#define O_HEBF   655360u
#define O_HET    3932160u
#define O_KE     7208960u
#define O_WAE    10485760u
#define O_WPROJT 10616832u
#define O_WIH    11010048u
#define O_EMBA   11534336u
#define O_WOUT   11730944u
#define O_XG     60882944u
#define O_HALLF  62455808u
#define O_HALLB  62849024u
#define O_QD     63045632u
#define O_EXPE   63242240u
#define O_FEAT   63856640u
#define O_AE     64446464u
#define O_PS     65060864u
#define O_SCALE  65062400u

extern "C" void kernel_launch(void* const* d_in, const int* in_sizes, int n_in,
                              void* d_out, int out_size, void* d_ws, size_t ws_size,
                              hipStream_t stream)
{
    const int*   inputs = (const int*)  d_in[0];
    const int*   src    = (const int*)  d_in[1];
    const float* h_e    = (const float*)d_in[2];
    const float* h0     = (const float*)d_in[3];
    const float* c0     = (const float*)d_in[4];
    const float* W_emb  = (const float*)d_in[5];
    const float* W_ih   = (const float*)d_in[6];
    const float* b_ih   = (const float*)d_in[7];
    const float* W_hh   = (const float*)d_in[8];
    const float* b_hh   = (const float*)d_in[9];
    const float* W_ae   = (const float*)d_in[10];
    const float* W_ad   = (const float*)d_in[11];
    const float* W_proj = (const float*)d_in[12];
    const float* W_u    = (const float*)d_in[13];
    const float* b_u    = (const float*)d_in[14];
    const float* b_out  = (const float*)d_in[15];
    const int*   pad_id = (const int*)  d_in[16];

    char* w = (char*)d_ws;
    bf16_t* whh_bf  = (bf16_t*)(w + O_WHH);
    bf16_t* wadT_bf = (bf16_t*)(w + O_WADT);
    bf16_t* he_bf   = (bf16_t*)(w + O_HEBF);
    bf16_t* heT_bf  = (bf16_t*)(w + O_HET);
    bf16_t* ke_bf   = (bf16_t*)(w + O_KE);
    bf16_t* wae_bf  = (bf16_t*)(w + O_WAE);
    bf16_t* wprojT  = (bf16_t*)(w + O_WPROJT);
    bf16_t* wih_bf  = (bf16_t*)(w + O_WIH);
    bf16_t* embA_bf = (bf16_t*)(w + O_EMBA);
    bf16_t* wout_bf = (bf16_t*)(w + O_WOUT);
    float*  xg      = (float*) (w + O_XG);
    float*  hallF   = (float*) (w + O_HALLF);
    bf16_t* hallB   = (bf16_t*)(w + O_HALLB);
    bf16_t* qdG     = (bf16_t*)(w + O_QD);
    float*  expE    = (float*) (w + O_EXPE);
    bf16_t* feat_bf = (bf16_t*)(w + O_FEAT);
    float*  Ae      = (float*) (w + O_AE);
    float*  ps      = (float*) (w + O_PS);
    float*  scale   = (float*) (w + O_SCALE);
    float*  out     = (float*)d_out;

    k_prep<<<1024, 256, 0, stream>>>(W_hh, W_ad, h_e, W_emb, W_proj, W_ae, W_ih, inputs,
                                     whh_bf, wadT_bf, he_bf, heT_bf,
                                     wae_bf, wih_bf, wprojT, embA_bf);
    // ke = h_e @ W_ae^T                       (M=6400, N=256, K=256)
    k_gemm<<<100, 256, 0, stream>>>(he_bf, nullptr, wae_bf, 6400, 256, 256, 2, 2,
                                    nullptr, ke_bf, nullptr, nullptr, nullptr);
    // W_out = tanh(W_emb @ W_proj)            (M=32000, N=768, K=256), A fp32 inline
    k_gemm<<<1500, 256, 0, stream>>>(nullptr, W_emb, wprojT, VOCABN, 768, 256, 6, 1,
                                     nullptr, wout_bf, nullptr, nullptr, nullptr);
    // xg = embA @ W_ih^T + b_ih + b_hh        (M=384, N=1024, K=256)
    k_gemm<<<24, 256, 0, stream>>>(embA_bf, nullptr, wih_bf, NROW, 1024, 256, 8, 0,
                                   xg, nullptr, b_ih, b_hh, nullptr);
    // sequential LSTM chain (only truly serial part)
    k_lstm<<<1, 1024, 0, stream>>>(whh_bf, xg, h0, c0, hallF, hallB);
    // qd = h_all @ W_attn_dec                 (M=384, N=256, K=256)
    k_gemm<<<6, 256, 0, stream>>>(hallB, nullptr, wadT_bf, NROW, 256, 256, 2, 2,
                                  nullptr, qdG, nullptr, nullptr, nullptr);
    // parallel attention tail
    k_escore<<<NROW, 256, 0, stream>>>(ke_bf, hallF, expE);
    k_attn2<<<NROW, 256, 0, stream>>>(expE, heT_bf, hallF, qdG, W_u, b_u,
                                      feat_bf, Ae, ps);
    // exp(logits + b_out), pad -> 0           (M=384, N=32000, K=768) -> d_out
    k_gemm<<<750, 256, 0, stream>>>(feat_bf, nullptr, wout_bf, NROW, VOCABN, 768, 250, 3,
                                    out, nullptr, b_out, nullptr, pad_id);
    k_rowsum<<<NROW, 256, 0, stream>>>(out, ps, scale);
    k_norm<<<2048, 256, 0, stream>>>(out, scale);
    k_copy<<<NROW, 256, 0, stream>>>(out, src, Ae, ps);
}

// Round 4
// 539.986 us; speedup vs baseline: 3.3028x; 1.1646x over previous
//
#include <hip/hip_runtime.h>
#include <cstdint>
#include <cstddef>

// ---------------- problem constants ----------------
#define TGT   24
#define BS    16
#define SRC   400
#define VOCABN 32000
#define DIM   256
#define NROW  (TGT*BS)   // 384

typedef __bf16 bf16_t;
typedef __bf16 v8bf __attribute__((ext_vector_type(8)));
typedef float  v4f  __attribute__((ext_vector_type(4)));

// ---------------- prep: dtype conversions / transposes / gather ----------------
__global__ void k_prep(const float* __restrict__ Whh, const float* __restrict__ Wad,
                       const float* __restrict__ he,  const float* __restrict__ Wemb,
                       const float* __restrict__ Wproj, const float* __restrict__ Wae,
                       const float* __restrict__ Wih, const int* __restrict__ inputs,
                       bf16_t* o_whh, bf16_t* o_wadT, bf16_t* o_he, bf16_t* o_heT,
                       bf16_t* o_wae, bf16_t* o_wih, bf16_t* o_wprojT, bf16_t* o_embA)
{
    const long S0=262144, S1=65536, S2=1638400, S3=1638400, S4=65536, S5=262144, S6=196608, S7=98304;
    const long total = S0+S1+S2+S3+S4+S5+S6+S7;
    for (long i = (long)blockIdx.x*blockDim.x + threadIdx.x; i < total;
         i += (long)gridDim.x*blockDim.x) {
        long j = i;
        if (j < S0) { o_whh[j] = (bf16_t)Whh[j]; continue; }           j -= S0;
        if (j < S1) { long n = j>>8, k = j&255; o_wadT[j] = (bf16_t)Wad[k*DIM + n]; continue; } j -= S1;
        if (j < S2) { o_he[j] = (bf16_t)he[j]; continue; }             j -= S2;
        if (j < S3) { // heT[b][d][s] = he[(s*BS+b)*DIM+d]
            long b = j / 102400, rem = j % 102400, d = rem / 400, s = rem % 400;
            o_heT[j] = (bf16_t)he[(s*BS + b)*DIM + d]; continue; }     j -= S3;
        if (j < S4) { o_wae[j] = (bf16_t)Wae[j]; continue; }           j -= S4;
        if (j < S5) { o_wih[j] = (bf16_t)Wih[j]; continue; }           j -= S5;
        if (j < S6) { long n = j>>8, k = j&255; o_wprojT[j] = (bf16_t)Wproj[k*768 + n]; continue; } j -= S6;
        { long r = j>>8, k = j&255; o_embA[j] = (bf16_t)Wemb[(long)inputs[r]*DIM + k]; }
    }
}

// ---------------- generic bf16 MFMA GEMM, 128x128 tile, BK=32 ----------------
// C[M,N] = A[M,K] @ B[N,K]^T  (row-major, K-contiguous). A32!=null: A read fp32.
// mode 3 additionally accumulates per-row sums of exp into rsum via atomics.
__global__ __launch_bounds__(256) void k_gemm(
    const bf16_t* __restrict__ A, const float* __restrict__ A32,
    const bf16_t* __restrict__ B,
    int M, int N, int K, int Ntiles, int mode,
    float* outF, bf16_t* outB,
    const float* __restrict__ bias0, const float* __restrict__ bias1,
    const int* __restrict__ padp, float* __restrict__ rsum)
{
    __shared__ bf16_t As[128*40];   // pitch 40 (pad 8) to break bank conflicts
    __shared__ bf16_t Bs[128*40];
    const int tid  = threadIdx.x;
    const int mt   = blockIdx.x / Ntiles, nt = blockIdx.x % Ntiles;
    const int m0   = mt*128, n0 = nt*128;
    const int lane = tid & 63, wave = tid >> 6;
    const int wm   = wave >> 1, wn = wave & 1;
    const int quad = lane >> 4, l16 = lane & 15;

    v4f acc[4][4];
#pragma unroll
    for (int i=0;i<4;i++)
#pragma unroll
        for (int j=0;j<4;j++) acc[i][j] = (v4f){0.f,0.f,0.f,0.f};

    const int srow = tid >> 1, shalf = tid & 1;       // staging: 2 threads/row
    const bf16_t* Ag   = A   ? A   + (size_t)(m0+srow)*K + shalf*16 : nullptr;
    const float*  Ag32 = A32 ? A32 + (size_t)(m0+srow)*K + shalf*16 : nullptr;
    const bf16_t* Bg = B + (size_t)(n0+srow)*K + shalf*16;
    bf16_t* AsW = &As[srow*40 + shalf*16];
    bf16_t* BsW = &Bs[srow*40 + shalf*16];

    for (int kc = 0; kc < K; kc += 32) {
        __syncthreads();
        uint4 b0 = *(const uint4*)(Bg + kc);
        uint4 b1 = *(const uint4*)(Bg + kc + 8);
        if (A32) {
            float4 f0 = *(const float4*)(Ag32 + kc);
            float4 f1 = *(const float4*)(Ag32 + kc + 4);
            float4 f2 = *(const float4*)(Ag32 + kc + 8);
            float4 f3 = *(const float4*)(Ag32 + kc + 12);
            v8bf u0, u1;
            u0[0]=(bf16_t)f0.x; u0[1]=(bf16_t)f0.y; u0[2]=(bf16_t)f0.z; u0[3]=(bf16_t)f0.w;
            u0[4]=(bf16_t)f1.x; u0[5]=(bf16_t)f1.y; u0[6]=(bf16_t)f1.z; u0[7]=(bf16_t)f1.w;
            u1[0]=(bf16_t)f2.x; u1[1]=(bf16_t)f2.y; u1[2]=(bf16_t)f2.z; u1[3]=(bf16_t)f2.w;
            u1[4]=(bf16_t)f3.x; u1[5]=(bf16_t)f3.y; u1[6]=(bf16_t)f3.z; u1[7]=(bf16_t)f3.w;
            *(v8bf*)AsW = u0; *(v8bf*)(AsW+8) = u1;
        } else {
            uint4 a0 = *(const uint4*)(Ag + kc);
            uint4 a1 = *(const uint4*)(Ag + kc + 8);
            *(uint4*)AsW = a0; *(uint4*)(AsW+8) = a1;
        }
        *(uint4*)BsW = b0; *(uint4*)(BsW+8) = b1;
        __syncthreads();
        v8bf af[4], bb[4];
#pragma unroll
        for (int i=0;i<4;i++) {
            af[i] = *(const v8bf*)&As[(wm*64 + i*16 + l16)*40 + quad*8];
            bb[i] = *(const v8bf*)&Bs[(wn*64 + i*16 + l16)*40 + quad*8];
        }
#pragma unroll
        for (int i=0;i<4;i++)
#pragma unroll
            for (int j=0;j<4;j++)
                acc[i][j] = __builtin_amdgcn_mfma_f32_16x16x32_bf16(af[i], bb[j], acc[i][j], 0,0,0);
    }

    const int pad = padp ? *padp : -1;
    float* rs = (float*)As;          // LDS reuse for mode-3 row partial sums
    if (mode == 3) {
        __syncthreads();             // everyone past last As read
        if (tid < 128) rs[tid] = 0.f;
        __syncthreads();
    }
#pragma unroll
    for (int i=0;i<4;i++) {
        float rloc[4] = {0.f,0.f,0.f,0.f};
#pragma unroll
        for (int j=0;j<4;j++) {
#pragma unroll
            for (int r=0;r<4;r++) {
                const int gr = m0 + wm*64 + i*16 + quad*4 + r;   // C/D row = quad*4+reg
                const int gc = n0 + wn*64 + j*16 + l16;          // C/D col = lane&15
                const float v = acc[i][j][r];
                if (mode == 0)      outF[(size_t)gr*N + gc] = v + bias0[gc] + bias1[gc];
                else if (mode == 1) outB[(size_t)gr*N + gc] = (bf16_t)tanhf(v);
                else if (mode == 2) outB[(size_t)gr*N + gc] = (bf16_t)v;
                else {
                    float ex = (gc == pad) ? 0.f : __expf(v + bias0[gc]);
                    outF[(size_t)gr*N + gc] = ex;
                    rloc[r] += ex;
                }
            }
        }
        if (mode == 3) {
#pragma unroll
            for (int r=0;r<4;r++)
                atomicAdd(&rs[wm*64 + i*16 + quad*4 + r], rloc[r]);
        }
    }
    if (mode == 3) {
        __syncthreads();
        if (tid < 128) atomicAdd(&rsum[m0 + tid], rs[tid]);
    }
}

// ---------------- sequential LSTM chain: ONE block, weight-resident ----------------
// 512 threads = 8 waves (2/SIMD, 256-VGPR cap). Wave w owns d-slice [w*32,w*32+32).
// Gate rows g*256+d: g=0,1 in registers (128 VGPR), g=2 streamed from L2 (loop-
// invariant addresses), g=3 in LDS (128 KB). MFMA 16x16x32: A = h (hi+lo bf16),
// C row = b (quad*4+r), C col = d-within-tile (lane&15).
__global__ __launch_bounds__(512, 2) void k_lstm(
    const bf16_t* __restrict__ Whh, const float* __restrict__ xg,
    const float* __restrict__ h0, const float* __restrict__ c0,
    float* __restrict__ hallF, bf16_t* __restrict__ hallB)
{
    __shared__ bf16_t wlds[65536];    // gate-3 tiles: [tile16][kc8][l16][quad*8]
    __shared__ bf16_t hhi[16][264];
    __shared__ bf16_t hlo[16][264];

    const int tid = threadIdx.x;
    const int w = tid >> 6, lane = tid & 63;
    const int l16 = lane & 15, quad = lane >> 4;

    // preload gate-3 weights into LDS (conflict-free layout)
    for (int idx = tid; idx < 8192; idx += 512) {
        int tl = idx >> 9, u = idx & 511;
        int kc = u >> 6, r16 = (u >> 2) & 15, q = u & 3;
        int grow = 768 + (tl >> 1)*32 + (tl & 1)*16 + r16;
        *(uint4*)&wlds[idx*8] = *(const uint4*)&Whh[(size_t)grow*DIM + kc*32 + q*8];
    }
    // preload gate-0/1 weights into registers: wreg[g*2+hf][kc]
    v8bf wreg[4][8];
#pragma unroll
    for (int g = 0; g < 2; ++g)
#pragma unroll
      for (int hf = 0; hf < 2; ++hf)
#pragma unroll
        for (int kc = 0; kc < 8; ++kc)
            wreg[g*2+hf][kc] = *(const v8bf*)&Whh[(size_t)(g*256 + w*32 + hf*16 + l16)*DIM + kc*32 + quad*8];

    for (int i = tid; i < 4096; i += 512) {
        int b = i >> 8, d = i & 255;
        float v = h0[b*DIM + d];
        bf16_t hi = (bf16_t)v;
        hhi[b][d] = hi; hlo[b][d] = (bf16_t)(v - (float)hi);
    }
    float c[2][4];
#pragma unroll
    for (int hf = 0; hf < 2; ++hf)
#pragma unroll
      for (int r = 0; r < 4; ++r)
        c[hf][r] = c0[(quad*4 + r)*DIM + w*32 + hf*16 + l16];
    __syncthreads();

    const bf16_t* g2base = Whh + (size_t)(512 + w*32 + l16)*DIM + quad*8;
    for (int step = 0; step < TGT; ++step) {
        // gate-2 weights: loop-invariant addresses -> L2-hot (or compiler-hoisted)
        v8bf ws[2][8];
#pragma unroll
        for (int hf = 0; hf < 2; ++hf)
#pragma unroll
          for (int kc = 0; kc < 8; ++kc)
            ws[hf][kc] = *(const v8bf*)(g2base + (size_t)hf*16*DIM + kc*32);

        v4f acc[4][2];
#pragma unroll
        for (int g = 0; g < 4; ++g)
#pragma unroll
          for (int hf = 0; hf < 2; ++hf) acc[g][hf] = (v4f){0.f,0.f,0.f,0.f};

#pragma unroll
        for (int kc = 0; kc < 8; ++kc) {
            v8bf ahi = *(const v8bf*)&hhi[l16][kc*32 + quad*8];
            v8bf alo = *(const v8bf*)&hlo[l16][kc*32 + quad*8];
#pragma unroll
            for (int g = 0; g < 2; ++g)
#pragma unroll
              for (int hf = 0; hf < 2; ++hf) {
                acc[g][hf] = __builtin_amdgcn_mfma_f32_16x16x32_bf16(ahi, wreg[g*2+hf][kc], acc[g][hf], 0,0,0);
                acc[g][hf] = __builtin_amdgcn_mfma_f32_16x16x32_bf16(alo, wreg[g*2+hf][kc], acc[g][hf], 0,0,0);
              }
#pragma unroll
            for (int hf = 0; hf < 2; ++hf) {
                acc[2][hf] = __builtin_amdgcn_mfma_f32_16x16x32_bf16(ahi, ws[hf][kc], acc[2][hf], 0,0,0);
                acc[2][hf] = __builtin_amdgcn_mfma_f32_16x16x32_bf16(alo, ws[hf][kc], acc[2][hf], 0,0,0);
                v8bf bl = *(const v8bf*)&wlds[(((w*2+hf)*8 + kc)*16 + l16)*32 + quad*8];
                acc[3][hf] = __builtin_amdgcn_mfma_f32_16x16x32_bf16(ahi, bl, acc[3][hf], 0,0,0);
                acc[3][hf] = __builtin_amdgcn_mfma_f32_16x16x32_bf16(alo, bl, acc[3][hf], 0,0,0);
            }
        }
        __syncthreads();   // all reads of old h complete
        const float* xgp = xg + (size_t)step*BS*1024;
#pragma unroll
        for (int hf = 0; hf < 2; ++hf) {
            const int d = w*32 + hf*16 + l16;
#pragma unroll
            for (int r = 0; r < 4; ++r) {
                const int b = quad*4 + r;
                const float gi = acc[0][hf][r] + xgp[b*1024 +       d];
                const float gf = acc[1][hf][r] + xgp[b*1024 + 256 + d];
                const float gg = acc[2][hf][r] + xgp[b*1024 + 512 + d];
                const float go = acc[3][hf][r] + xgp[b*1024 + 768 + d];
                const float si = 1.f/(1.f+__expf(-gi));
                const float sf = 1.f/(1.f+__expf(-gf));
                const float so = 1.f/(1.f+__expf(-go));
                const float cn = sf*c[hf][r] + si*tanhf(gg);
                const float hn = so*tanhf(cn);
                c[hf][r] = cn;
                const bf16_t hi = (bf16_t)hn;
                hhi[b][d] = hi; hlo[b][d] = (bf16_t)(hn - (float)hi);
                hallF[(size_t)(step*BS + b)*DIM + d] = hn;
                hallB[(size_t)(step*BS + b)*DIM + d] = hi;
            }
        }
        __syncthreads();
    }
}

// ---------------- expE[t,b,s] = exp(ke[s,b,:] . h[t,b,:]) — fully parallel ------
__global__ __launch_bounds__(256) void k_escore(const bf16_t* __restrict__ ke,
                                                const float* __restrict__ hallF,
                                                float* __restrict__ expE)
{
    const int t = blockIdx.x >> 4, b = blockIdx.x & 15;
    const int tid = threadIdx.x;
    __shared__ float hS[DIM];
    hS[tid] = hallF[(size_t)(t*BS + b)*DIM + tid];
    __syncthreads();
    for (int s = tid; s < SRC; s += 256) {
        const v8bf* kp = (const v8bf*)(ke + ((size_t)s*BS + b)*DIM);
        float e = 0.f;
#pragma unroll 8
        for (int m=0;m<32;m++) {
            v8bf kv = kp[m];
#pragma unroll
            for (int i=0;i<8;i++) e += (float)kv[i]*hS[m*8+i];
        }
        expE[((size_t)t*BS + b)*SRC + s] = __expf(e);
    }
}

// ---------------- per-(t,b) attention tail ----------------
__global__ __launch_bounds__(256) void k_attn2(
    const float* __restrict__ expE, const bf16_t* __restrict__ heT,
    const float* __restrict__ hallF, const bf16_t* __restrict__ qdG,
    const float* __restrict__ wu, const float* __restrict__ bu,
    bf16_t* __restrict__ feat, float* __restrict__ Ae, float* __restrict__ ps)
{
    const int t = blockIdx.x >> 4, b = blockIdx.x & 15;
    const int tid = threadIdx.x;
    __shared__ float hS[DIM], qdS[DIM], eeS[SRC], adS[TGT];
    __shared__ float red[4], misc[2];

    hS[tid]  = hallF[(size_t)(t*BS + b)*DIM + tid];
    qdS[tid] = (float)qdG[(size_t)(t*BS + b)*DIM + tid];
    __syncthreads();

    for (int s = tid; s < SRC; s += 256) {
        float prev = 0.f;
        for (int tp = 0; tp < t; ++tp) prev += expE[((size_t)tp*BS + b)*SRC + s];
        float my = expE[((size_t)t*BS + b)*SRC + s];
        eeS[s] = (t == 0) ? my : my / prev;
    }
    __syncthreads();
    {   // esum
        float pa = 0.f;
        for (int s = tid; s < SRC; s += 256) pa += eeS[s];
#pragma unroll
        for (int o=32;o>0;o>>=1) pa += __shfl_down(pa, o);
        if ((tid & 63) == 0) red[tid>>6] = pa;
        __syncthreads();
        if (tid == 0) misc[0] = 1.f/(red[0]+red[1]+red[2]+red[3]);
        __syncthreads();
    }
    const float inv_es = misc[0];
    for (int s = tid; s < SRC; s += 256)
        Ae[((size_t)t*BS + b)*SRC + s] = eeS[s] * inv_es;

    float ce;
    {
        const v8bf* hp = (const v8bf*)(heT + ((size_t)b*DIM + tid)*SRC);
        float acc = 0.f;
#pragma unroll 10
        for (int m=0;m<50;m++) {
            v8bf hv = hp[m];
#pragma unroll
            for (int i=0;i<8;i++) acc += (float)hv[i]*eeS[m*8+i];
        }
        ce = acc * inv_es;
    }

    {
        const int wv = tid >> 6, ln = tid & 63;
        for (int tau = wv; tau <= t; tau += 4) {
            float4 a = *(const float4*)(hallF + ((size_t)(tau*BS + b))*DIM + ln*4);
            float e = a.x*qdS[ln*4] + a.y*qdS[ln*4+1] + a.z*qdS[ln*4+2] + a.w*qdS[ln*4+3];
#pragma unroll
            for (int o=32;o>0;o>>=1) e += __shfl_down(e, o);
            if (ln == 0) adS[tau] = __expf(e);
        }
    }
    __syncthreads();
    if (tid < 64) {
        float v = (tid <= t) ? adS[tid] : 0.f;
#pragma unroll
        for (int o=32;o>0;o>>=1) v += __shfl_down(v, o);
        if (tid == 0) misc[1] = 1.f/v;
    }
    __syncthreads();
    float cd = 0.f;
    for (int tau = 0; tau <= t; ++tau)
        cd += adS[tau] * hallF[((size_t)(tau*BS + b))*DIM + tid];
    cd *= misc[1];
    if (t == 0) cd = 0.f;

    const float hd = hS[tid];
    const size_t fr = ((size_t)t*BS + b)*768;
    feat[fr + tid]       = (bf16_t)hd;
    feat[fr + 256 + tid] = (bf16_t)ce;
    feat[fr + 512 + tid] = (bf16_t)cd;
    float pw = hd*wu[tid] + ce*wu[256 + tid] + cd*wu[512 + tid];
#pragma unroll
    for (int o=32;o>0;o>>=1) pw += __shfl_down(pw, o);
    if ((tid & 63) == 0) red[tid>>6] = pw;
    __syncthreads();
    if (tid == 0) {
        float s = red[0]+red[1]+red[2]+red[3];
        ps[t*BS + b] = 1.f/(1.f+__expf(-(s + bu[0])));
    }
}

// ---------------- scale[r] = ps[r] / rowsum[r] (sums from GEMM epilogue) --------
__global__ void k_scale(const float* __restrict__ rsum, const float* __restrict__ ps,
                        float* __restrict__ scale)
{
    const int r = threadIdx.x;
    if (r < NROW) scale[r] = ps[r] / rsum[r];
}

// ---------------- scores = exp_logits * scale[r] ----------------
__global__ void k_norm(float* __restrict__ out, const float* __restrict__ scale)
{
    const long n4 = (long)NROW*VOCABN/4;
    for (long i = (long)blockIdx.x*blockDim.x + threadIdx.x; i < n4;
         i += (long)gridDim.x*blockDim.x) {
        const long r = (i*4)/VOCABN;
        float4 v = ((float4*)out)[i];
        const float sc = scale[r];
        v.x*=sc; v.y*=sc; v.z*=sc; v.w*=sc;
        ((float4*)out)[i] = v;
    }
}

// ---------------- copy mechanism scatter ----------------
__global__ __launch_bounds__(256) void k_copy(float* __restrict__ out,
                                              const int* __restrict__ src,
                                              const float* __restrict__ Ae,
                                              const float* __restrict__ ps)
{
    const int r = blockIdx.x;        // r = t*BS + b
    const int b = r & (BS-1);
    const float p = ps[r];
    for (int s = threadIdx.x; s < SRC; s += 256) {
        const int v = src[s*BS + b];
        atomicAdd(&out[(size_t)r*VOCABN + v], Ae[(size_t)r*SRC + s] * p);
    }
}

// ---------------- workspace layout (bytes, 16B-aligned) ----------------
#define O_WHH    0u
#define O_WADT   524288u
#define O_HEBF   655360u
#define O_HET    3932160u
#define O_KE     7208960u
#define O_WAE    10485760u
#define O_WPROJT 10616832u
#define O_WIH    11010048u
#define O_EMBA   11534336u
#define O_WOUT   11730944u
#define O_XG     60882944u
#define O_HALLF  62455808u
#define O_HALLB  62849024u
#define O_QD     63045632u
#define O_EXPE   63242240u
#define O_FEAT   63856640u
#define O_AE     64446464u
#define O_PS     65060864u
#define O_SCALE  65062400u
#define O_RSUM   65063936u   // 1536 B, zeroed each call

extern "C" void kernel_launch(void* const* d_in, const int* in_sizes, int n_in,
                              void* d_out, int out_size, void* d_ws, size_t ws_size,
                              hipStream_t stream)
{
    const int*   inputs = (const int*)  d_in[0];
    const int*   src    = (const int*)  d_in[1];
    const float* h_e    = (const float*)d_in[2];
    const float* h0     = (const float*)d_in[3];
    const float* c0     = (const float*)d_in[4];
    const float* W_emb  = (const float*)d_in[5];
    const float* W_ih   = (const float*)d_in[6];
    const float* b_ih   = (const float*)d_in[7];
    const float* W_hh   = (const float*)d_in[8];
    const float* b_hh   = (const float*)d_in[9];
    const float* W_ae   = (const float*)d_in[10];
    const float* W_ad   = (const float*)d_in[11];
    const float* W_proj = (const float*)d_in[12];
    const float* W_u    = (const float*)d_in[13];
    const float* b_u    = (const float*)d_in[14];
    const float* b_out  = (const float*)d_in[15];
    const int*   pad_id = (const int*)  d_in[16];

    char* w = (char*)d_ws;
    bf16_t* whh_bf  = (bf16_t*)(w + O_WHH);
    bf16_t* wadT_bf = (bf16_t*)(w + O_WADT);
    bf16_t* he_bf   = (bf16_t*)(w + O_HEBF);
    bf16_t* heT_bf  = (bf16_t*)(w + O_HET);
    bf16_t* ke_bf   = (bf16_t*)(w + O_KE);
    bf16_t* wae_bf  = (bf16_t*)(w + O_WAE);
    bf16_t* wprojT  = (bf16_t*)(w + O_WPROJT);
    bf16_t* wih_bf  = (bf16_t*)(w + O_WIH);
    bf16_t* embA_bf = (bf16_t*)(w + O_EMBA);
    bf16_t* wout_bf = (bf16_t*)(w + O_WOUT);
    float*  xg      = (float*) (w + O_XG);
    float*  hallF   = (float*) (w + O_HALLF);
    bf16_t* hallB   = (bf16_t*)(w + O_HALLB);
    bf16_t* qdG     = (bf16_t*)(w + O_QD);
    float*  expE    = (float*) (w + O_EXPE);
    bf16_t* feat_bf = (bf16_t*)(w + O_FEAT);
    float*  Ae      = (float*) (w + O_AE);
    float*  ps      = (float*) (w + O_PS);
    float*  scale   = (float*) (w + O_SCALE);
    float*  rsum    = (float*) (w + O_RSUM);
    float*  out     = (float*)d_out;

    k_prep<<<1024, 256, 0, stream>>>(W_hh, W_ad, h_e, W_emb, W_proj, W_ae, W_ih, inputs,
                                     whh_bf, wadT_bf, he_bf, heT_bf,
                                     wae_bf, wih_bf, wprojT, embA_bf);
    hipMemsetAsync(w + O_RSUM, 0, 1536, stream);
    // ke = h_e @ W_ae^T                       (M=6400, N=256, K=256)
    k_gemm<<<100, 256, 0, stream>>>(he_bf, nullptr, wae_bf, 6400, 256, 256, 2, 2,
                                    nullptr, ke_bf, nullptr, nullptr, nullptr, nullptr);
    // W_out = tanh(W_emb @ W_proj)            (M=32000, N=768, K=256), A fp32 inline
    k_gemm<<<1500, 256, 0, stream>>>(nullptr, W_emb, wprojT, VOCABN, 768, 256, 6, 1,
                                     nullptr, wout_bf, nullptr, nullptr, nullptr, nullptr);
    // xg = embA @ W_ih^T + b_ih + b_hh        (M=384, N=1024, K=256)
    k_gemm<<<24, 256, 0, stream>>>(embA_bf, nullptr, wih_bf, NROW, 1024, 256, 8, 0,
                                   xg, nullptr, b_ih, b_hh, nullptr, nullptr);
    // sequential LSTM chain (weight-resident)
    k_lstm<<<1, 512, 0, stream>>>(whh_bf, xg, h0, c0, hallF, hallB);
    // qd = h_all @ W_attn_dec                 (M=384, N=256, K=256)
    k_gemm<<<6, 256, 0, stream>>>(hallB, nullptr, wadT_bf, NROW, 256, 256, 2, 2,
                                  nullptr, qdG, nullptr, nullptr, nullptr, nullptr);
    // parallel attention tail
    k_escore<<<NROW, 256, 0, stream>>>(ke_bf, hallF, expE);
    k_attn2<<<NROW, 256, 0, stream>>>(expE, heT_bf, hallF, qdG, W_u, b_u,
                                      feat_bf, Ae, ps);
    // exp(logits + b_out), pad -> 0, + fused row sums  (M=384, N=32000, K=768)
    k_gemm<<<750, 256, 0, stream>>>(feat_bf, nullptr, wout_bf, NROW, VOCABN, 768, 250, 3,
                                    out, nullptr, b_out, nullptr, pad_id, rsum);
    k_scale<<<1, 384, 0, stream>>>(rsum, ps, scale);
    k_norm<<<2048, 256, 0, stream>>>(out, scale);
    k_copy<<<NROW, 256, 0, stream>>>(out, src, Ae, ps);
}